// Round 1
// baseline (9.718 us; speedup 1.0000x reference)
//
#include <hip/hip_runtime.h>

// Reference output = softmax(logits, axis=1) with logits shape [N, 1].
// Softmax over a size-1 axis is identically 1.0 for every row, independent
// of all inputs. The whole GNN is dead code w.r.t. the output.
// Therefore: fill d_out (N floats) with 1.0f.

__global__ void fill_ones_kernel(float* __restrict__ out, int n) {
    int i = blockIdx.x * blockDim.x + threadIdx.x;
    int i4 = i << 2;
    if (i4 + 3 < n) {
        *reinterpret_cast<float4*>(out + i4) = make_float4(1.0f, 1.0f, 1.0f, 1.0f);
    } else if (i4 < n) {
        for (int j = i4; j < n; ++j) out[j] = 1.0f;
    }
}

extern "C" void kernel_launch(void* const* d_in, const int* in_sizes, int n_in,
                              void* d_out, int out_size, void* d_ws, size_t ws_size,
                              hipStream_t stream) {
    (void)d_in; (void)in_sizes; (void)n_in; (void)d_ws; (void)ws_size;
    float* out = (float*)d_out;
    const int n = out_size;              // 50000
    const int threads = 256;
    const int vec = (n + 3) / 4;         // float4 elements
    const int blocks = (vec + threads - 1) / threads;
    fill_ones_kernel<<<blocks, threads, 0, stream>>>(out, n);
}